// Round 7
// baseline (559.562 us; speedup 1.0000x reference)
//
#include <hip/hip_runtime.h>

typedef unsigned short u16;
typedef __bf16 bf16x8 __attribute__((ext_vector_type(8)));
typedef float f32x4 __attribute__((ext_vector_type(4)));
typedef float f32x16 __attribute__((ext_vector_type(16)));

// Problem constants: B=8, N=2048, DH=512
#define SEQN 2048
#define DHID 512

static __device__ __forceinline__ float bf2f(u16 u) {
    union { unsigned int i; float f; } c; c.i = ((unsigned int)u) << 16; return c.f;
}
static __device__ __forceinline__ u16 f2bf(float f) {
    union { float f; unsigned int i; } c; c.f = f;
    unsigned int x = c.i;
    return (u16)((x + 0x7fffu + ((x >> 16) & 1u)) >> 16);
}

// async global->LDS, 16B per lane, LDS dest = wave-uniform base + lane*16
static __device__ __forceinline__ void gld_lds16(const u16* g, u16* l) {
    __builtin_amdgcn_global_load_lds(
        (__attribute__((address_space(1))) void*)(g),
        (__attribute__((address_space(3))) void*)(l), 16, 0, 0);
}

// ---------------------------------------------------------------------------
// fp32 -> bf16 conversion (n multiple of 8)
// ---------------------------------------------------------------------------
__global__ __launch_bounds__(256) void cvt_kernel(const float* __restrict__ src,
                                                  u16* __restrict__ dst, int n) {
    int i = (blockIdx.x * 256 + threadIdx.x) * 8;
    if (i >= n) return;
    float4 a = *(const float4*)(src + i);
    float4 b = *(const float4*)(src + i + 4);
    union { uint4 u; u16 s[8]; } o;
    o.s[0] = f2bf(a.x); o.s[1] = f2bf(a.y); o.s[2] = f2bf(a.z); o.s[3] = f2bf(a.w);
    o.s[4] = f2bf(b.x); o.s[5] = f2bf(b.y); o.s[6] = f2bf(b.z); o.s[7] = f2bf(b.w);
    *(uint4*)(dst + i) = o.u;
}

// fp32 [K][N] -> bf16 transposed [N][K]
__global__ __launch_bounds__(256) void cvt_t_kernel(const float* __restrict__ src,
                                                    u16* __restrict__ dst, int K, int N) {
    int idx = blockIdx.x * 256 + threadIdx.x;
    if (idx >= K * N) return;
    int n = idx / K, k = idx - n * K;
    dst[idx] = f2bf(src[(size_t)k * N + n]);
}

// ---------------------------------------------------------------------------
// hop_emb row means (fp32 in): hm[j] = mean_d hop_emb[j][d]
// ---------------------------------------------------------------------------
__global__ void hmean_kernel(const float* __restrict__ hop, float* __restrict__ hm) {
    int j = blockIdx.x, t = threadIdx.x;           // 64 threads
    const float* p = hop + (size_t)j * DHID + t * 8;
    float4 a = *(const float4*)p;
    float4 b = *(const float4*)(p + 4);
    float s = a.x + a.y + a.z + a.w + b.x + b.y + b.z + b.w;
#pragma unroll
    for (int m = 1; m < 64; m <<= 1) s += __shfl_xor(s, m);
    if (t == 0) hm[j] = s * (1.0f / (float)DHID);
}

// ---------------------------------------------------------------------------
// BT MFMA GEMM: C[M,N] = A[M,K] * Bt[N,K]^T + epilogue  (A,Bt,C bf16)
// Tile 128x128x32, 256 threads (4 waves as 2x2 of 64x64), 16x16x32 MFMA.
// EPI_QKV: N=1536 concat [Q|K|Vt]; sel = gn>>9 is block-uniform.
// ---------------------------------------------------------------------------
enum { EPI_BIAS = 0, EPI_RELU = 1, EPI_PLAIN = 3, EPI_BIAS_T = 4, EPI_QKV = 5 };

template <int EPI>
__global__ __launch_bounds__(256) void gemm_bt(
    const u16* __restrict__ A, const u16* __restrict__ Bt, u16* __restrict__ C,
    const float* __restrict__ bias,
    int K, int lda, int ldb, int ldc,
    u16* __restrict__ Qo, u16* __restrict__ Ko, u16* __restrict__ Vto,
    const float* __restrict__ bq_, const float* __restrict__ bk_,
    const float* __restrict__ bv_)
{
    __shared__ u16 As[128 * 32];   // 8 KB, [row][k], row stride 64 B
    __shared__ u16 Bs[128 * 32];   // 8 KB, [n][k]

    const int tid = threadIdx.x;
    const u16* Ab = A;
    const u16* Bb = Bt;

    const int bm0 = blockIdx.y * 128, bn0 = blockIdx.x * 128;
    const int wid = tid >> 6, lane = tid & 63, quad = lane >> 4, l16 = lane & 15;
    const int wm = (wid >> 1) * 64, wn = (wid & 1) * 64;
    const int srow = lane >> 2;            // 0..15: row within 16-row chunk
    const int skof = (lane & 3) * 8;       // k element offset (8 bf16 = 16 B)

    f32x4 acc[4][4];
#pragma unroll
    for (int i = 0; i < 4; ++i)
#pragma unroll
        for (int j = 0; j < 4; ++j) acc[i][j] = (f32x4){0.f, 0.f, 0.f, 0.f};

    for (int k0 = 0; k0 < K; k0 += 32) {
#pragma unroll
        for (int it = 0; it < 2; ++it) {
            int c = wid * 2 + it;          // wave-uniform
            gld_lds16(Ab + (size_t)(bm0 + c * 16 + srow) * lda + k0 + skof,
                      &As[c * 512]);
        }
#pragma unroll
        for (int it = 0; it < 2; ++it) {
            int c = wid * 2 + it;
            gld_lds16(Bb + (size_t)(bn0 + c * 16 + srow) * ldb + k0 + skof,
                      &Bs[c * 512]);
        }
        __syncthreads();

        bf16x8 af[4], bfr[4];
#pragma unroll
        for (int i = 0; i < 4; ++i)
            af[i] = *(const bf16x8*)&As[(wm + i * 16 + l16) * 32 + quad * 8];
#pragma unroll
        for (int j = 0; j < 4; ++j)
            bfr[j] = *(const bf16x8*)&Bs[(wn + j * 16 + l16) * 32 + quad * 8];
#pragma unroll
        for (int i = 0; i < 4; ++i)
#pragma unroll
            for (int j = 0; j < 4; ++j)
                acc[i][j] = __builtin_amdgcn_mfma_f32_16x16x32_bf16(af[i], bfr[j], acc[i][j], 0, 0, 0);
        __syncthreads();
    }

    // ---- epilogue: C/D layout col=lane&15, row=quad*4+reg ----
#pragma unroll
    for (int i = 0; i < 4; ++i) {
#pragma unroll
        for (int j = 0; j < 4; ++j) {
            const int gn = bn0 + wn + j * 16 + l16;
            const int gm0 = bm0 + wm + i * 16 + quad * 4;
            if constexpr (EPI == EPI_BIAS || EPI == EPI_RELU) {
                const float b = bias[gn];
#pragma unroll
                for (int r = 0; r < 4; ++r) {
                    float v = acc[i][j][r] + b;
                    if constexpr (EPI == EPI_RELU) v = fmaxf(v, 0.f);
                    C[(size_t)(gm0 + r) * ldc + gn] = f2bf(v);
                }
            } else if constexpr (EPI == EPI_BIAS_T) {
                const float b = bias[gn];
                const int bb = gm0 >> 11, n = gm0 & 2047;
                ushort4 o;
                o.x = f2bf(acc[i][j][0] + b);
                o.y = f2bf(acc[i][j][1] + b);
                o.z = f2bf(acc[i][j][2] + b);
                o.w = f2bf(acc[i][j][3] + b);
                *(ushort4*)&C[((size_t)bb * 512 + gn) * 2048 + n] = o;
            } else if constexpr (EPI == EPI_QKV) {
                const int sel = gn >> 9;     // block-uniform (bn0 128-aligned)
                const int n = gn & 511;
                if (sel == 0) {
                    const float b = bq_[n];
#pragma unroll
                    for (int r = 0; r < 4; ++r)
                        Qo[(size_t)(gm0 + r) * DHID + n] = f2bf(acc[i][j][r] + b);
                } else if (sel == 1) {
                    const float b = bk_[n];
#pragma unroll
                    for (int r = 0; r < 4; ++r)
                        Ko[(size_t)(gm0 + r) * DHID + n] = f2bf(acc[i][j][r] + b);
                } else {
                    const float b = bv_[n];
                    const int bb = gm0 >> 11, nn2 = gm0 & 2047;
                    ushort4 o;
                    o.x = f2bf(acc[i][j][0] + b);
                    o.y = f2bf(acc[i][j][1] + b);
                    o.z = f2bf(acc[i][j][2] + b);
                    o.w = f2bf(acc[i][j][3] + b);
                    *(ushort4*)&Vto[((size_t)bb * 512 + n) * 2048 + nn2] = o;
                }
            } else {
#pragma unroll
                for (int r = 0; r < 4; ++r)
                    C[(size_t)(gm0 + r) * ldc + gn] = f2bf(acc[i][j][r]);
            }
        }
    }
}

// ---------------------------------------------------------------------------
// Fused attention v9: block = (batch bx, 32 Q-rows by). 4 waves.
// QK^T (unchanged from v8): wave w -> q-group g=w>>1 (16 rows), kv-half
// ch=w&1; 16 MFMA 16x16x32, 16 K-frag reads; softmax fills shared P[32x40].
// PV (new): wave w -> d-quarter w*128 for ALL 32 q-rows via mfma_32x32x16:
// 8 MFMA, 8 V B-frag reads + 2 P A-frag reads (vs 16+1 with 16x16x32) —
// 32x32x16 does 2x FLOPs per 16B/lane operand read. acc = 4 x f32x16 = 64.
// XOR chunk-swizzle (both-sides, rule #21) on Ks and Vs: global SOURCE chunk
// (lane&3)^(srow&3) pre-swizzled in gld_lds (LDS dest stays linear), read
// side applies ^(row&3) -> K/V read phases spread over 4 bank-groups not 2.
// Layouts (derived from verified 16x16x32 mappings + m74 C/D):
//   32x32x16 A: row=lane&31, k=(lane>>5)*8+j   B: col=lane&31, k=(lane>>5)*8+j
//   32x32x16 C/D: col=lane&31, row=(reg&3)+8*(reg>>2)+4*(lane>>5)
// Barriers: B1/B2 __syncthreads (v6b invariant: own-vmcnt drained at every
// barrier -> all waves' gld_lds data visible after it); B3 lgkm-only raw
// barrier for P visibility (K restage vmcnt stays in flight).
// LDS 68096B: Ks 32KB | Vs 32KB | P 2.5KB -> 2 blocks/CU.
// ---------------------------------------------------------------------------
__global__ __launch_bounds__(256, 2) void attn_kernel(
    const u16* __restrict__ Q, const u16* __restrict__ K, const u16* __restrict__ Vt,
    const float* __restrict__ adj, const float* __restrict__ hm,
    u16* __restrict__ AO)
{
    extern __shared__ u16 lds[];                 // 68096 B
    u16* Ks = lds;                               // [ds16][c2][16 rows x 32 u16]
    u16* Vs = lds + 16384;                       // [d512][kv32] (chunk-swizzled)
    u16* Pm = lds + 32768;                       // shared P: 32 rows x 40 u16

    const int tid = threadIdx.x, wid = tid >> 6, lane = tid & 63;
    const int quad = lane >> 4, l16 = lane & 15;
    const int b = blockIdx.x;                    // batch -> XCD affinity
    const int qblk = blockIdx.y * 32;            // block's 32 Q-rows
    const int g = wid >> 1;                      // q-group for QK^T
    const int q0 = qblk + g * 16;
    const int ch = wid & 1;                      // kv-half for QK^T
    const int srow = lane >> 2;
    const int skosw = (((lane & 3) ^ (srow & 3)) * 8);  // pre-swizzled chunk

    const u16* Qg = Q + (size_t)b * SEQN * DHID;
    const u16* Kg = K + (size_t)b * SEQN * DHID;
    const u16* Vg = Vt + (size_t)b * DHID * SEQN;
    const float* adjg = adj + (size_t)b * SEQN * SEQN;
    u16* AOg = AO + (size_t)b * SEQN * DHID;
    const float* arow = adjg + (size_t)(q0 + quad * 4) * SEQN;

    const float scale = 0.044194173824159216f;   // 1/sqrt(512)

    // Q fragments (A-layout 16x16x32): lane holds Q[q0+l16][ds*32+quad*8+j]
    bf16x8 qf[16];
#pragma unroll
    for (int ds = 0; ds < 16; ++ds)
        qf[ds] = *(const bf16x8*)(Qg + (size_t)(q0 + l16) * DHID + ds * 32 + quad * 8);

    f32x16 oacc[4];
#pragma unroll
    for (int t = 0; t < 4; ++t)
#pragma unroll
        for (int r = 0; r < 16; ++r) oacc[t][r] = 0.f;
    float lsum[4] = {0.f, 0.f, 0.f, 0.f};

    // ---- prologue: issue Ks = K[0] staging (chunk-swizzled source) ----
#pragma unroll
    for (int i = 0; i < 8; ++i) {
        int id = wid * 8 + i, ds = id >> 1, c = id & 1;
        gld_lds16(Kg + (size_t)(c * 16 + srow) * DHID + ds * 32 + skosw,
                  &Ks[ds * 1024 + c * 512]);
    }

    for (int kt = 0; kt < 64; ++kt) {
        const int kv0 = kt * 32;

        // [B1] drains own vmcnt (K[kt] stage) + lgkm (prev PV/P reads), barrier.
        __syncthreads();

        // ---- stage Vs[kt] async (chunk-swizzled source; drained at B2) ----
#pragma unroll
        for (int i = 0; i < 8; ++i) {
            int id = wid * 8 + i;                // d-rows id*16..id*16+16
            gld_lds16(Vg + (size_t)(id * 16 + srow) * SEQN + kv0 + skosw,
                      &Vs[id * 512]);
        }

        // ---- scalar loads for the wave's 16 kv-cols (used post-B2) ----
        float hv = hm[kv0 + ch * 16 + l16] * scale;
        float av[4];
#pragma unroll
        for (int r = 0; r < 4; ++r)
            av[r] = arow[(size_t)r * SEQN + kv0 + ch * 16 + l16];

        // ---- QK^T: S 16x16 (wave's kv-half), swizzled Ks reads ----
        f32x4 sa = {0.f,0.f,0.f,0.f}, sb = {0.f,0.f,0.f,0.f};
#pragma unroll
        for (int ds = 0; ds < 16; ds += 2) {
            bf16x8 k0 = *(const bf16x8*)&Ks[ds * 1024 + ch * 512 + l16 * 32
                                            + ((quad ^ (l16 & 3)) * 8)];
            sa = __builtin_amdgcn_mfma_f32_16x16x32_bf16(qf[ds], k0, sa, 0, 0, 0);
            bf16x8 k1 = *(const bf16x8*)&Ks[(ds + 1) * 1024 + ch * 512 + l16 * 32
                                            + ((quad ^ (l16 & 3)) * 8)];
            sb = __builtin_amdgcn_mfma_f32_16x16x32_bf16(qf[ds + 1], k1, sb, 0, 0, 0);
        }
        f32x4 s = sa + sb;

        // [B2] drains own vmcnt (Vs + scalars) + lgkm (Ks reads), barrier.
        __syncthreads();

        // ---- stage Ks[kt+1] NOW (drained at next B1; softmax+PV cover) ----
        if (kt < 63) {
#pragma unroll
            for (int i = 0; i < 8; ++i) {
                int id = wid * 8 + i, ds = id >> 1, c = id & 1;
                gld_lds16(Kg + (size_t)(kv0 + 32 + c * 16 + srow) * DHID + ds * 32 + skosw,
                          &Ks[ds * 1024 + c * 512]);
            }
        }
        __builtin_amdgcn_sched_barrier(0);       // keep K issue above softmax/PV

        // ---- softmax: 4 exp, write wave's P cells into shared Pm ----
#pragma unroll
        for (int r = 0; r < 4; ++r) {
            float p = __expf(s[r] * av[r] * hv);
            lsum[r] += p;                         // wave's kv-half partial sum
            Pm[(g * 16 + quad * 4 + r) * 40 + ch * 16 + l16] = f2bf(p);
        }

        // [B3] P complete across all 4 waves: own lgkm drain + raw barrier.
        // (K gld_lds vmcnt intentionally NOT drained here.)
        asm volatile("s_waitcnt lgkmcnt(0)" ::: "memory");
        __builtin_amdgcn_s_barrier();
        __builtin_amdgcn_sched_barrier(0);

        // ---- PV: O[32 x d-quarter] += P[32x32] @ V[32 x 128], 32x32x16 ----
        // A-frags: P rows=lane&31, k = h*16 + (lane>>5)*8 .. +8
        bf16x8 pa0 = *(const bf16x8*)&Pm[(lane & 31) * 40 + (lane >> 5) * 8];
        bf16x8 pa1 = *(const bf16x8*)&Pm[(lane & 31) * 40 + 16 + (lane >> 5) * 8];
#pragma unroll
        for (int t = 0; t < 4; ++t) {
            const int d = wid * 128 + t * 32 + (lane & 31);
            // B-frags: V col=d, kv-chunk (h*2 + lane>>5) ^ swizzle(d&3)
            bf16x8 v0 = *(const bf16x8*)&Vs[d * 32 + (((lane >> 5) ^ (d & 3)) * 8)];
            oacc[t] = __builtin_amdgcn_mfma_f32_32x32x16_bf16(pa0, v0, oacc[t], 0, 0, 0);
            bf16x8 v1 = *(const bf16x8*)&Vs[d * 32 + (((2 + (lane >> 5)) ^ (d & 3)) * 8)];
            oacc[t] = __builtin_amdgcn_mfma_f32_32x32x16_bf16(pa1, v1, oacc[t], 0, 0, 0);
        }
    }

    // ---- finalize: combine kv-half row sums across waves, normalize ----
#pragma unroll
    for (int r = 0; r < 4; ++r) {
#pragma unroll
        for (int m = 1; m < 16; m <<= 1) lsum[r] += __shfl_xor(lsum[r], m);
    }
    __syncthreads();                             // last PV P/Vs reads done
    float* SUMS = (float*)Pm;                    // [2 halves][32 rows]
    if (l16 == 0) {
#pragma unroll
        for (int r = 0; r < 4; ++r)
            SUMS[ch * 32 + g * 16 + quad * 4 + r] = lsum[r];
    }
    __syncthreads();
    float inv16[16];
#pragma unroll
    for (int rg = 0; rg < 16; ++rg) {
        int row = (rg & 3) + 8 * (rg >> 2) + 4 * (lane >> 5);
        inv16[rg] = 1.f / (SUMS[row] + SUMS[32 + row]);
    }
#pragma unroll
    for (int t = 0; t < 4; ++t) {
#pragma unroll
        for (int rg = 0; rg < 16; ++rg) {
            int row = (rg & 3) + 8 * (rg >> 2) + 4 * (lane >> 5);
            AOg[(size_t)(qblk + row) * DHID + wid * 128 + t * 32 + (lane & 31)] =
                f2bf(oacc[t][rg] * inv16[rg]);
        }
    }
}

// ---------------------------------------------------------------------------
// LN1: x = LN(a + Hf) * g + be   (a bf16, Hf fp32, out bf16)
// ---------------------------------------------------------------------------
__global__ __launch_bounds__(256) void ln_hf32_kernel(
    const u16* __restrict__ a, const float* __restrict__ Hf,
    const float* __restrict__ g, const float* __restrict__ be,
    u16* __restrict__ out)
{
    size_t row = blockIdx.x;
    int t = threadIdx.x, wid = t >> 6, lane = t & 63;
    unsigned int va = *(const unsigned int*)(a + row * (size_t)DHID + t * 2);
    float2 h = *(const float2*)(Hf + row * (size_t)DHID + t * 2);
    float x0 = bf2f((u16)(va & 0xffff)) + h.x;
    float x1 = bf2f((u16)(va >> 16)) + h.y;
    float s = x0 + x1, sq = x0 * x0 + x1 * x1;
#pragma unroll
    for (int m = 1; m < 64; m <<= 1) { s += __shfl_xor(s, m); sq += __shfl_xor(sq, m); }
    __shared__ float rs[4], rq[4];
    if (lane == 0) { rs[wid] = s; rq[wid] = sq; }
    __syncthreads();
    s = rs[0] + rs[1] + rs[2] + rs[3];
    sq = rq[0] + rq[1] + rq[2] + rq[3];
    float mean = s * (1.f / (float)DHID);
    float var = sq * (1.f / (float)DHID) - mean * mean;
    float rstd = rsqrtf(var + 1e-5f);
    float2 vg = *(const float2*)(g + t * 2);
    float2 vbe = *(const float2*)(be + t * 2);
    float y0 = (x0 - mean) * rstd * vg.x + vbe.x;
    float y1 = (x1 - mean) * rstd * vg.y + vbe.y;
    unsigned int o = (unsigned int)f2bf(y0) | ((unsigned int)f2bf(y1) << 16);
    *(unsigned int*)(out + row * (size_t)DHID + t * 2) = o;
}

// ---------------------------------------------------------------------------
// LN2: out = LN(a + b) * g + be   (a,b bf16, out fp32)
// ---------------------------------------------------------------------------
__global__ __launch_bounds__(256) void ln_kernel_f32out(
    const u16* __restrict__ a, const u16* __restrict__ bp,
    const float* __restrict__ g, const float* __restrict__ be,
    float* __restrict__ out)
{
    size_t row = blockIdx.x;
    int t = threadIdx.x, wid = t >> 6, lane = t & 63;
    unsigned int va = *(const unsigned int*)(a + row * (size_t)DHID + t * 2);
    unsigned int vb = *(const unsigned int*)(bp + row * (size_t)DHID + t * 2);
    float x0 = bf2f((u16)(va & 0xffff)) + bf2f((u16)(vb & 0xffff));
    float x1 = bf2f((u16)(va >> 16)) + bf2f((u16)(vb >> 16));
    float s = x0 + x1, sq = x0 * x0 + x1 * x1;
#pragma unroll
    for (int m = 1; m < 64; m <<= 1) { s += __shfl_xor(s, m); sq += __shfl_xor(sq, m); }
    __shared__ float rs[4], rq[4];
    if (lane == 0) { rs[wid] = s; rq[wid] = sq; }
    __syncthreads();
    s = rs[0] + rs[1] + rs[2] + rs[3];
    sq = rq[0] + rq[1] + rq[2] + rq[3];
    float mean = s * (1.f / (float)DHID);
    float var = sq * (1.f / (float)DHID) - mean * mean;
    float rstd = rsqrtf(var + 1e-5f);
    float2 vg = *(const float2*)(g + t * 2);
    float2 vbe = *(const float2*)(be + t * 2);
    float y0 = (x0 - mean) * rstd * vg.x + vbe.x;
    float y1 = (x1 - mean) * rstd * vg.y + vbe.y;
    *(float2*)(out + row * (size_t)DHID + t * 2) = make_float2(y0, y1);
}

// ---------------------------------------------------------------------------
extern "C" void kernel_launch(void* const* d_in, const int* in_sizes, int n_in,
                              void* d_out, int out_size, void* d_ws, size_t ws_size,
                              hipStream_t stream) {
    const float* H   = (const float*)d_in[0];
    const float* adj = (const float*)d_in[1];
    const float* hop = (const float*)d_in[2];
    const float* Wq  = (const float*)d_in[3];
    const float* bq  = (const float*)d_in[4];
    const float* Wk  = (const float*)d_in[5];
    const float* bk  = (const float*)d_in[6];
    const float* Wv  = (const float*)d_in[7];
    const float* bv  = (const float*)d_in[8];
    const float* W1  = (const float*)d_in[9];
    const float* b1  = (const float*)d_in[10];
    const float* W2  = (const float*)d_in[11];
    const float* b2  = (const float*)d_in[12];
    const float* g1  = (const float*)d_in[13];
    const float* be1 = (const float*)d_in[14];
    const float* g2  = (const float*)d_in[15];
    const float* be2 = (const float*)d_in[16];

    const size_t MiB = 1ull << 20;
    char* w = (char*)d_ws;
    float* hm   = (float*)w;                      // 8 KB
    u16* Hb    = (u16*)(w + 1 * MiB);             // 16 MiB
    u16* Wqkvt = (u16*)(w + 17 * MiB);            // 1.5 MiB [Wq^T|Wk^T|Wv^T]
    u16* W1t   = (u16*)(w + 18 * MiB + 512 * 1024); // 1 MiB
    u16* W2t   = (u16*)(w + 19 * MiB + 512 * 1024); // 1 MiB
    u16* Q     = (u16*)(w + 21 * MiB);            // 16 MiB
    u16* Kb    = (u16*)(w + 37 * MiB);            // 16 MiB
    u16* Vt    = (u16*)(w + 53 * MiB);            // 16 MiB  [b][512][2048]
    u16* AO    = (u16*)(w + 69 * MiB);            // 16 MiB
    u16* HID   = (u16*)(w + 85 * MiB);            // 32 MiB -> total 117 MiB
    // aliases (lifetimes disjoint):
    u16* X   = Kb;   // LN1 output (K dead after attention)
    u16* F2  = Vt;   // ffn2 output (V dead after attention)

    const int BN = 8, N = SEQN, D = DHID;

    // fp32 -> bf16 conversions (weights transposed, QKV concatenated)
    cvt_kernel<<<(BN * N * D) / (8 * 256), 256, 0, stream>>>(H, Hb, BN * N * D);
    cvt_t_kernel<<<(D * D + 255) / 256, 256, 0, stream>>>(Wq, Wqkvt, D, D);
    cvt_t_kernel<<<(D * D + 255) / 256, 256, 0, stream>>>(Wk, Wqkvt + D * D, D, D);
    cvt_t_kernel<<<(D * D + 255) / 256, 256, 0, stream>>>(Wv, Wqkvt + 2 * D * D, D, D);
    cvt_t_kernel<<<(D * 2 * D + 255) / 256, 256, 0, stream>>>(W1, W1t, D, 2 * D);
    cvt_t_kernel<<<(2 * D * D + 255) / 256, 256, 0, stream>>>(W2, W2t, 2 * D, D);

    hmean_kernel<<<N, 64, 0, stream>>>(hop, hm);

    // fused QKV: C[16384,1536] over [Q|K|Vt] outputs
    gemm_bt<EPI_QKV><<<dim3(12, 128, 1), 256, 0, stream>>>(
        Hb, Wqkvt, nullptr, nullptr, D, D, D, 0, Q, Kb, Vt, bq, bk, bv);

    // fused attention: 512 blocks (8 batches x 64 stripes of 32 rows), 2/CU
    attn_kernel<<<dim3(8, 64), 256, 68096, stream>>>(Q, Kb, Vt, adj, hm, AO);

    // x = LN(attn_out + H)
    ln_hf32_kernel<<<BN * N, 256, 0, stream>>>(AO, H, g1, be1, X);

    // hid = relu(x @ W1 + b1)
    gemm_bt<EPI_RELU><<<dim3(8, 128, 1), 256, 0, stream>>>(
        X, W1t, HID, b1, D, D, D, 2 * D, nullptr, nullptr, nullptr, nullptr, nullptr, nullptr);

    // f2 = hid @ W2 + b2
    gemm_bt<EPI_BIAS><<<dim3(4, 128, 1), 256, 0, stream>>>(
        HID, W2t, F2, b2, 2 * D, 2 * D, 2 * D, D, nullptr, nullptr, nullptr, nullptr, nullptr, nullptr);

    // out = LN(f2 + x)  -> fp32 d_out
    ln_kernel_f32out<<<BN * N, 256, 0, stream>>>(F2, X, g2, be2, (float*)d_out);
}

// Round 8
// 549.784 us; speedup vs baseline: 1.0178x; 1.0178x over previous
//
#include <hip/hip_runtime.h>

typedef unsigned short u16;
typedef __bf16 bf16x8 __attribute__((ext_vector_type(8)));
typedef float f32x4 __attribute__((ext_vector_type(4)));

// Problem constants: B=8, N=2048, DH=512
#define SEQN 2048
#define DHID 512

static __device__ __forceinline__ float bf2f(u16 u) {
    union { unsigned int i; float f; } c; c.i = ((unsigned int)u) << 16; return c.f;
}
static __device__ __forceinline__ u16 f2bf(float f) {
    union { float f; unsigned int i; } c; c.f = f;
    unsigned int x = c.i;
    return (u16)((x + 0x7fffu + ((x >> 16) & 1u)) >> 16);
}

// async global->LDS, 16B per lane, LDS dest = wave-uniform base + lane*16
static __device__ __forceinline__ void gld_lds16(const u16* g, u16* l) {
    __builtin_amdgcn_global_load_lds(
        (__attribute__((address_space(1))) void*)(g),
        (__attribute__((address_space(3))) void*)(l), 16, 0, 0);
}

// ---------------------------------------------------------------------------
// fp32 -> bf16 conversion (n multiple of 8)
// ---------------------------------------------------------------------------
__global__ __launch_bounds__(256) void cvt_kernel(const float* __restrict__ src,
                                                  u16* __restrict__ dst, int n) {
    int i = (blockIdx.x * 256 + threadIdx.x) * 8;
    if (i >= n) return;
    float4 a = *(const float4*)(src + i);
    float4 b = *(const float4*)(src + i + 4);
    union { uint4 u; u16 s[8]; } o;
    o.s[0] = f2bf(a.x); o.s[1] = f2bf(a.y); o.s[2] = f2bf(a.z); o.s[3] = f2bf(a.w);
    o.s[4] = f2bf(b.x); o.s[5] = f2bf(b.y); o.s[6] = f2bf(b.z); o.s[7] = f2bf(b.w);
    *(uint4*)(dst + i) = o.u;
}

// fp32 [K][N] -> bf16 transposed [N][K]
__global__ __launch_bounds__(256) void cvt_t_kernel(const float* __restrict__ src,
                                                    u16* __restrict__ dst, int K, int N) {
    int idx = blockIdx.x * 256 + threadIdx.x;
    if (idx >= K * N) return;
    int n = idx / K, k = idx - n * K;
    dst[idx] = f2bf(src[(size_t)k * N + n]);
}

// ---------------------------------------------------------------------------
// hop_emb row means (fp32 in): hm[j] = mean_d hop_emb[j][d]
// ---------------------------------------------------------------------------
__global__ void hmean_kernel(const float* __restrict__ hop, float* __restrict__ hm) {
    int j = blockIdx.x, t = threadIdx.x;           // 64 threads
    const float* p = hop + (size_t)j * DHID + t * 8;
    float4 a = *(const float4*)p;
    float4 b = *(const float4*)(p + 4);
    float s = a.x + a.y + a.z + a.w + b.x + b.y + b.z + b.w;
#pragma unroll
    for (int m = 1; m < 64; m <<= 1) s += __shfl_xor(s, m);
    if (t == 0) hm[j] = s * (1.0f / (float)DHID);
}

// ---------------------------------------------------------------------------
// BT MFMA GEMM v2: C[M,N] = A[M,K] * Bt[N,K]^T + epilogue  (A,Bt,C bf16)
// Tile 128x128x32, 256 threads (4 waves as 2x2 of 64x64), 16x16x32 MFMA.
// DOUBLE-BUFFERED 2-phase (T3 minimum recipe): per K-step, one
// __syncthreads, then issue STAGE of the NEXT K-tile into buf^1 while
// computing buf. The old structure staged into a single buffer and
// immediately drained vmcnt at the barrier -> fully exposed stage latency
// (~500cy x K/32 iters). Hazards: buf[cur] gld_lds writes (issued prev
// iter) are own-vmcnt drained by each wave inside the top __syncthreads ->
// visible to all after barrier; buf^1 overwrite vs its last ds_reads (prev
// iter) covered by the same barrier's lgkm drain. LDS 32KB -> 4-5 blocks/CU.
// EPI_QKV: N=1536 concat [Q|K|Vt]; sel = gn>>9 is block-uniform.
// ---------------------------------------------------------------------------
enum { EPI_BIAS = 0, EPI_RELU = 1, EPI_PLAIN = 3, EPI_BIAS_T = 4, EPI_QKV = 5 };

template <int EPI>
__global__ __launch_bounds__(256) void gemm_bt(
    const u16* __restrict__ A, const u16* __restrict__ Bt, u16* __restrict__ C,
    const float* __restrict__ bias,
    int K, int lda, int ldb, int ldc,
    u16* __restrict__ Qo, u16* __restrict__ Ko, u16* __restrict__ Vto,
    const float* __restrict__ bq_, const float* __restrict__ bk_,
    const float* __restrict__ bv_)
{
    __shared__ u16 As[2][128 * 32];   // 16 KB, [row][k], row stride 64 B
    __shared__ u16 Bs[2][128 * 32];   // 16 KB, [n][k]

    const int tid = threadIdx.x;
    const u16* Ab = A;
    const u16* Bb = Bt;

    const int bm0 = blockIdx.y * 128, bn0 = blockIdx.x * 128;
    const int wid = tid >> 6, lane = tid & 63, quad = lane >> 4, l16 = lane & 15;
    const int wm = (wid >> 1) * 64, wn = (wid & 1) * 64;
    const int srow = lane >> 2;            // 0..15: row within 16-row chunk
    const int skof = (lane & 3) * 8;       // k element offset (8 bf16 = 16 B)

    f32x4 acc[4][4];
#pragma unroll
    for (int i = 0; i < 4; ++i)
#pragma unroll
        for (int j = 0; j < 4; ++j) acc[i][j] = (f32x4){0.f, 0.f, 0.f, 0.f};

    // prologue: stage K-tile 0 into buf 0
#pragma unroll
    for (int it = 0; it < 2; ++it) {
        int c = wid * 2 + it;              // wave-uniform
        gld_lds16(Ab + (size_t)(bm0 + c * 16 + srow) * lda + skof, &As[0][c * 512]);
    }
#pragma unroll
    for (int it = 0; it < 2; ++it) {
        int c = wid * 2 + it;
        gld_lds16(Bb + (size_t)(bn0 + c * 16 + srow) * ldb + skof, &Bs[0][c * 512]);
    }

    int cur = 0;
    for (int k0 = 0; k0 < K; k0 += 32, cur ^= 1) {
        // top barrier: drains own vmcnt (buf[cur] stage) + lgkm (prev reads)
        __syncthreads();

        // stage NEXT K-tile into buf^1 (drained at next top barrier;
        // latency covered by the frag reads + MFMA below)
        if (k0 + 32 < K) {
#pragma unroll
            for (int it = 0; it < 2; ++it) {
                int c = wid * 2 + it;
                gld_lds16(Ab + (size_t)(bm0 + c * 16 + srow) * lda + k0 + 32 + skof,
                          &As[cur ^ 1][c * 512]);
            }
#pragma unroll
            for (int it = 0; it < 2; ++it) {
                int c = wid * 2 + it;
                gld_lds16(Bb + (size_t)(bn0 + c * 16 + srow) * ldb + k0 + 32 + skof,
                          &Bs[cur ^ 1][c * 512]);
            }
        }
        __builtin_amdgcn_sched_barrier(0);   // keep stage issue above compute

        bf16x8 af[4], bfr[4];
#pragma unroll
        for (int i = 0; i < 4; ++i)
            af[i] = *(const bf16x8*)&As[cur][(wm + i * 16 + l16) * 32 + quad * 8];
#pragma unroll
        for (int j = 0; j < 4; ++j)
            bfr[j] = *(const bf16x8*)&Bs[cur][(wn + j * 16 + l16) * 32 + quad * 8];
#pragma unroll
        for (int i = 0; i < 4; ++i)
#pragma unroll
            for (int j = 0; j < 4; ++j)
                acc[i][j] = __builtin_amdgcn_mfma_f32_16x16x32_bf16(af[i], bfr[j], acc[i][j], 0, 0, 0);
    }

    // ---- epilogue: C/D layout col=lane&15, row=quad*4+reg ----
#pragma unroll
    for (int i = 0; i < 4; ++i) {
#pragma unroll
        for (int j = 0; j < 4; ++j) {
            const int gn = bn0 + wn + j * 16 + l16;
            const int gm0 = bm0 + wm + i * 16 + quad * 4;
            if constexpr (EPI == EPI_BIAS || EPI == EPI_RELU) {
                const float b = bias[gn];
#pragma unroll
                for (int r = 0; r < 4; ++r) {
                    float v = acc[i][j][r] + b;
                    if constexpr (EPI == EPI_RELU) v = fmaxf(v, 0.f);
                    C[(size_t)(gm0 + r) * ldc + gn] = f2bf(v);
                }
            } else if constexpr (EPI == EPI_BIAS_T) {
                const float b = bias[gn];
                const int bb = gm0 >> 11, n = gm0 & 2047;
                ushort4 o;
                o.x = f2bf(acc[i][j][0] + b);
                o.y = f2bf(acc[i][j][1] + b);
                o.z = f2bf(acc[i][j][2] + b);
                o.w = f2bf(acc[i][j][3] + b);
                *(ushort4*)&C[((size_t)bb * 512 + gn) * 2048 + n] = o;
            } else if constexpr (EPI == EPI_QKV) {
                const int sel = gn >> 9;     // block-uniform (bn0 128-aligned)
                const int n = gn & 511;
                if (sel == 0) {
                    const float b = bq_[n];
#pragma unroll
                    for (int r = 0; r < 4; ++r)
                        Qo[(size_t)(gm0 + r) * DHID + n] = f2bf(acc[i][j][r] + b);
                } else if (sel == 1) {
                    const float b = bk_[n];
#pragma unroll
                    for (int r = 0; r < 4; ++r)
                        Ko[(size_t)(gm0 + r) * DHID + n] = f2bf(acc[i][j][r] + b);
                } else {
                    const float b = bv_[n];
                    const int bb = gm0 >> 11, nn2 = gm0 & 2047;
                    ushort4 o;
                    o.x = f2bf(acc[i][j][0] + b);
                    o.y = f2bf(acc[i][j][1] + b);
                    o.z = f2bf(acc[i][j][2] + b);
                    o.w = f2bf(acc[i][j][3] + b);
                    *(ushort4*)&Vto[((size_t)bb * 512 + n) * 2048 + nn2] = o;
                }
            } else {
#pragma unroll
                for (int r = 0; r < 4; ++r)
                    C[(size_t)(gm0 + r) * ldc + gn] = f2bf(acc[i][j][r]);
            }
        }
    }
}

// ---------------------------------------------------------------------------
// Fused attention v8 (best measured: 192us): block = (batch bx, 32 Q-rows by).
// 4 waves: wave w -> rows (w>>1)*16; kv-half (QK^T) and d-half (PV) = w&1.
// Each wave computes only its kv-half S[16x16] (16 MFMA, 16 K reads); the
// d-half pair shares P through LDS.
//   B1 (__syncthreads): drains K[kt] stage (issued last iter, covered by
//       softmax+PV); orders prev PV reads before Vs restage.
//   B2 (__syncthreads): drains Vs (v5 lesson: own-vmcnt drained at barrier).
//   B3 (lgkm + raw s_barrier): P visibility; K restage vmcnt stays in flight.
// LDS 68096B: Ks 32KB | Vs 32KB | Pb 2.5KB -> 2 blocks/CU.
// ---------------------------------------------------------------------------
__global__ __launch_bounds__(256, 2) void attn_kernel(
    const u16* __restrict__ Q, const u16* __restrict__ K, const u16* __restrict__ Vt,
    const float* __restrict__ adj, const float* __restrict__ hm,
    u16* __restrict__ AO)
{
    extern __shared__ u16 lds[];                 // 68096 B
    u16* Ks = lds;                               // [ds16][c2][16 rows x 32 u16]
    u16* Vs = lds + 16384;                       // [d512][kv32]
    u16* Pb = lds + 32768;                       // 2 row-groups x 640 u16

    const int tid = threadIdx.x, wid = tid >> 6, lane = tid & 63;
    const int quad = lane >> 4, l16 = lane & 15;
    const int b = blockIdx.x;                    // batch -> XCD affinity
    const int q0 = blockIdx.y * 32 + (wid >> 1) * 16;  // wave's 16 Q-rows
    const int ch = wid & 1;                      // kv-half (QK^T) / d-half (PV)
    const int D0 = ch * 256;
    const int srow = lane >> 2, sko = (lane & 3) * 8;

    const u16* Qg = Q + (size_t)b * SEQN * DHID;
    const u16* Kg = K + (size_t)b * SEQN * DHID;
    const u16* Vg = Vt + (size_t)b * DHID * SEQN;
    const float* adjg = adj + (size_t)b * SEQN * SEQN;
    u16* AOg = AO + (size_t)b * SEQN * DHID;
    const float* arow = adjg + (size_t)(q0 + quad * 4) * SEQN;
    u16* Pg = Pb + (wid >> 1) * 640;             // shared by the d-half pair

    const float scale = 0.044194173824159216f;   // 1/sqrt(512)

    // Q fragments (A-layout): lane holds Q[q0+l16][ds*32+quad*8+j]
    bf16x8 qf[16];
#pragma unroll
    for (int ds = 0; ds < 16; ++ds)
        qf[ds] = *(const bf16x8*)(Qg + (size_t)(q0 + l16) * DHID + ds * 32 + quad * 8);

    f32x4 oacc[16];
#pragma unroll
    for (int dt = 0; dt < 16; ++dt) oacc[dt] = (f32x4){0.f, 0.f, 0.f, 0.f};
    float lsum[4] = {0.f, 0.f, 0.f, 0.f};

    // ---- prologue: issue Ks = K[0] staging; drained by first B1 ----
#pragma unroll
    for (int i = 0; i < 8; ++i) {
        int id = wid * 8 + i, ds = id >> 1, c = id & 1;
        gld_lds16(Kg + (size_t)(c * 16 + srow) * DHID + ds * 32 + sko,
                  &Ks[ds * 1024 + c * 512]);
    }

    for (int kt = 0; kt < 64; ++kt) {
        const int kv0 = kt * 32;

        // [B1] drains own vmcnt (K[kt] stage) + lgkm (prev PV/pf reads), barrier.
        __syncthreads();

        // ---- stage Vs[kt] async (drained at B2, covered by QK^T) ----
#pragma unroll
        for (int i = 0; i < 8; ++i) {
            int id = wid * 8 + i;                // d-rows id*16..id*16+16
            gld_lds16(Vg + (size_t)(id * 16 + srow) * SEQN + kv0 + sko,
                      &Vs[id * 512]);
        }

        // ---- scalar loads for the wave's 16 kv-cols (used post-B2) ----
        float hv = hm[kv0 + ch * 16 + l16] * scale;
        float av[4];
#pragma unroll
        for (int r = 0; r < 4; ++r)
            av[r] = arow[(size_t)r * SEQN + kv0 + ch * 16 + l16];

        // ---- QK^T: S 16x16 (wave's kv-half), 2 chains, reads Ks[.][ch] ----
        f32x4 sa = {0.f,0.f,0.f,0.f}, sb = {0.f,0.f,0.f,0.f};
#pragma unroll
        for (int ds = 0; ds < 16; ds += 2) {
            bf16x8 k0 = *(const bf16x8*)&Ks[ds * 1024 + ch * 512 + l16 * 32 + quad * 8];
            sa = __builtin_amdgcn_mfma_f32_16x16x32_bf16(qf[ds], k0, sa, 0, 0, 0);
            bf16x8 k1 = *(const bf16x8*)&Ks[(ds + 1) * 1024 + ch * 512 + l16 * 32 + quad * 8];
            sb = __builtin_amdgcn_mfma_f32_16x16x32_bf16(qf[ds + 1], k1, sb, 0, 0, 0);
        }
        f32x4 s = sa + sb;

        // [B2] drains own vmcnt (Vs + scalars) + lgkm (Ks reads), barrier.
        __syncthreads();

        // ---- stage Ks[kt+1] NOW (drained at next B1; softmax+PV cover) ----
        if (kt < 63) {
#pragma unroll
            for (int i = 0; i < 8; ++i) {
                int id = wid * 8 + i, ds = id >> 1, c = id & 1;
                gld_lds16(Kg + (size_t)(kv0 + 32 + c * 16 + srow) * DHID + ds * 32 + sko,
                          &Ks[ds * 1024 + c * 512]);
            }
        }
        __builtin_amdgcn_sched_barrier(0);       // keep K issue above softmax/PV

        // ---- softmax: 4 exp, write wave's P columns into shared Pg ----
#pragma unroll
        for (int r = 0; r < 4; ++r) {
            float p = __expf(s[r] * av[r] * hv);
            lsum[r] += p;                         // wave's kv-half partial sum
            Pg[(quad * 4 + r) * 40 + ch * 16 + l16] = f2bf(p);
        }

        // [B3] P complete across the pair: own lgkm drain + raw barrier.
        // (P is plain ds_write -> visible after barrier; K gld_lds vmcnt
        //  intentionally NOT drained here.)
        asm volatile("s_waitcnt lgkmcnt(0)" ::: "memory");
        __builtin_amdgcn_s_barrier();
        __builtin_amdgcn_sched_barrier(0);

        bf16x8 pf = *(const bf16x8*)&Pg[l16 * 40 + quad * 8];

        // ---- PV: O[16 x 256] += P[16x32] @ V[32 x d-half] ----
#pragma unroll
        for (int dt = 0; dt < 16; ++dt) {
            bf16x8 vf = *(const bf16x8*)&Vs[(D0 + dt * 16 + l16) * 32 + quad * 8];
            oacc[dt] = __builtin_amdgcn_mfma_f32_16x16x32_bf16(pf, vf, oacc[dt], 0, 0, 0);
        }
    }

    // ---- finalize: reduce kv-half sums over l16 group, combine across the
    //      d-half pair via LDS, normalize, store ----
#pragma unroll
    for (int r = 0; r < 4; ++r) {
#pragma unroll
        for (int m = 1; m < 16; m <<= 1) lsum[r] += __shfl_xor(lsum[r], m);
    }
    __syncthreads();                             // last PV/pf reads done
    float* SUMS = (float*)Pb;                    // [4 waves][16 rows]
    if (l16 == 0) {
#pragma unroll
        for (int r = 0; r < 4; ++r) SUMS[wid * 16 + quad * 4 + r] = lsum[r];
    }
    __syncthreads();
#pragma unroll
    for (int r = 0; r < 4; ++r)
        lsum[r] = 1.f / (lsum[r] + SUMS[(wid ^ 1) * 16 + quad * 4 + r]);

#pragma unroll
    for (int dt = 0; dt < 16; ++dt) {
#pragma unroll
        for (int r = 0; r < 4; ++r) {
            AOg[(size_t)(q0 + quad * 4 + r) * DHID + D0 + dt * 16 + l16] =
                f2bf(oacc[dt][r] * lsum[r]);
        }
    }
}

// ---------------------------------------------------------------------------
// LN1: x = LN(a + Hf) * g + be   (a bf16, Hf fp32, out bf16)
// ---------------------------------------------------------------------------
__global__ __launch_bounds__(256) void ln_hf32_kernel(
    const u16* __restrict__ a, const float* __restrict__ Hf,
    const float* __restrict__ g, const float* __restrict__ be,
    u16* __restrict__ out)
{
    size_t row = blockIdx.x;
    int t = threadIdx.x, wid = t >> 6, lane = t & 63;
    unsigned int va = *(const unsigned int*)(a + row * (size_t)DHID + t * 2);
    float2 h = *(const float2*)(Hf + row * (size_t)DHID + t * 2);
    float x0 = bf2f((u16)(va & 0xffff)) + h.x;
    float x1 = bf2f((u16)(va >> 16)) + h.y;
    float s = x0 + x1, sq = x0 * x0 + x1 * x1;
#pragma unroll
    for (int m = 1; m < 64; m <<= 1) { s += __shfl_xor(s, m); sq += __shfl_xor(sq, m); }
    __shared__ float rs[4], rq[4];
    if (lane == 0) { rs[wid] = s; rq[wid] = sq; }
    __syncthreads();
    s = rs[0] + rs[1] + rs[2] + rs[3];
    sq = rq[0] + rq[1] + rq[2] + rq[3];
    float mean = s * (1.f / (float)DHID);
    float var = sq * (1.f / (float)DHID) - mean * mean;
    float rstd = rsqrtf(var + 1e-5f);
    float2 vg = *(const float2*)(g + t * 2);
    float2 vbe = *(const float2*)(be + t * 2);
    float y0 = (x0 - mean) * rstd * vg.x + vbe.x;
    float y1 = (x1 - mean) * rstd * vg.y + vbe.y;
    unsigned int o = (unsigned int)f2bf(y0) | ((unsigned int)f2bf(y1) << 16);
    *(unsigned int*)(out + row * (size_t)DHID + t * 2) = o;
}

// ---------------------------------------------------------------------------
// LN2: out = LN(a + b) * g + be   (a,b bf16, out fp32)
// ---------------------------------------------------------------------------
__global__ __launch_bounds__(256) void ln_kernel_f32out(
    const u16* __restrict__ a, const u16* __restrict__ bp,
    const float* __restrict__ g, const float* __restrict__ be,
    float* __restrict__ out)
{
    size_t row = blockIdx.x;
    int t = threadIdx.x, wid = t >> 6, lane = t & 63;
    unsigned int va = *(const unsigned int*)(a + row * (size_t)DHID + t * 2);
    unsigned int vb = *(const unsigned int*)(bp + row * (size_t)DHID + t * 2);
    float x0 = bf2f((u16)(va & 0xffff)) + bf2f((u16)(vb & 0xffff));
    float x1 = bf2f((u16)(va >> 16)) + bf2f((u16)(vb >> 16));
    float s = x0 + x1, sq = x0 * x0 + x1 * x1;
#pragma unroll
    for (int m = 1; m < 64; m <<= 1) { s += __shfl_xor(s, m); sq += __shfl_xor(sq, m); }
    __shared__ float rs[4], rq[4];
    if (lane == 0) { rs[wid] = s; rq[wid] = sq; }
    __syncthreads();
    s = rs[0] + rs[1] + rs[2] + rs[3];
    sq = rq[0] + rq[1] + rq[2] + rq[3];
    float mean = s * (1.f / (float)DHID);
    float var = sq * (1.f / (float)DHID) - mean * mean;
    float rstd = rsqrtf(var + 1e-5f);
    float2 vg = *(const float2*)(g + t * 2);
    float2 vbe = *(const float2*)(be + t * 2);
    float y0 = (x0 - mean) * rstd * vg.x + vbe.x;
    float y1 = (x1 - mean) * rstd * vg.y + vbe.y;
    *(float2*)(out + row * (size_t)DHID + t * 2) = make_float2(y0, y1);
}

// ---------------------------------------------------------------------------
extern "C" void kernel_launch(void* const* d_in, const int* in_sizes, int n_in,
                              void* d_out, int out_size, void* d_ws, size_t ws_size,
                              hipStream_t stream) {
    const float* H   = (const float*)d_in[0];
    const float* adj = (const float*)d_in[1];
    const float* hop = (const float*)d_in[2];
    const float* Wq  = (const float*)d_in[3];
    const float* bq  = (const float*)d_in[4];
    const float* Wk  = (const float*)d_in[5];
    const float* bk  = (const float*)d_in[6];
    const float* Wv  = (const float*)d_in[7];
    const float* bv  = (const float*)d_in[8];
    const float* W1  = (const float*)d_in[9];
    const float* b1  = (const float*)d_in[10];
    const float* W2  = (const float*)d_in[11];
    const float* b2  = (const float*)d_in[12];
    const float* g1  = (const float*)d_in[13];
    const float* be1 = (const float*)d_in[14];
    const float* g2  = (const float*)d_in[15];
    const float* be2 = (const float*)d_in[16];

    const size_t MiB = 1ull << 20;
    char* w = (char*)d_ws;
    float* hm   = (float*)w;                      // 8 KB
    u16* Hb    = (u16*)(w + 1 * MiB);             // 16 MiB
    u16* Wqkvt = (u16*)(w + 17 * MiB);            // 1.5 MiB [Wq^T|Wk^T|Wv^T]
    u16* W1t   = (u16*)(w + 18 * MiB + 512 * 1024); // 1 MiB
    u16* W2t   = (u16*)(w + 19 * MiB + 512 * 1024); // 1 MiB
    u16* Q     = (u16*)(w + 21 * MiB);            // 16 MiB
    u16* Kb    = (u16*)(w + 37 * MiB);            // 16 MiB
    u16* Vt    = (u16*)(w + 53 * MiB);            // 16 MiB  [b][512][2048]
    u16* AO    = (u16*)(w + 69 * MiB);            // 16 MiB
    u16* HID   = (u16*)(w + 85 * MiB);            // 32 MiB -> total 117 MiB
    // aliases (lifetimes disjoint):
    u16* X   = Kb;   // LN1 output (K dead after attention)
    u16* F2  = Vt;   // ffn2 output (V dead after attention)

    const int BN = 8, N = SEQN, D = DHID;

    // fp32 -> bf16 conversions (weights transposed, QKV concatenated)
    cvt_kernel<<<(BN * N * D) / (8 * 256), 256, 0, stream>>>(H, Hb, BN * N * D);
    cvt_t_kernel<<<(D * D + 255) / 256, 256, 0, stream>>>(Wq, Wqkvt, D, D);
    cvt_t_kernel<<<(D * D + 255) / 256, 256, 0, stream>>>(Wk, Wqkvt + D * D, D, D);
    cvt_t_kernel<<<(D * D + 255) / 256, 256, 0, stream>>>(Wv, Wqkvt + 2 * D * D, D, D);
    cvt_t_kernel<<<(D * 2 * D + 255) / 256, 256, 0, stream>>>(W1, W1t, D, 2 * D);
    cvt_t_kernel<<<(2 * D * D + 255) / 256, 256, 0, stream>>>(W2, W2t, 2 * D, D);

    hmean_kernel<<<N, 64, 0, stream>>>(hop, hm);

    // fused QKV: C[16384,1536] over [Q|K|Vt] outputs
    gemm_bt<EPI_QKV><<<dim3(12, 128, 1), 256, 0, stream>>>(
        Hb, Wqkvt, nullptr, nullptr, D, D, D, 0, Q, Kb, Vt, bq, bk, bv);

    // fused attention: 512 blocks (8 batches x 64 stripes of 32 rows), 2/CU
    attn_kernel<<<dim3(8, 64), 256, 68096, stream>>>(Q, Kb, Vt, adj, hm, AO);

    // x = LN(attn_out + H)
    ln_hf32_kernel<<<BN * N, 256, 0, stream>>>(AO, H, g1, be1, X);

    // hid = relu(x @ W1 + b1)
    gemm_bt<EPI_RELU><<<dim3(8, 128, 1), 256, 0, stream>>>(
        X, W1t, HID, b1, D, D, D, 2 * D, nullptr, nullptr, nullptr, nullptr, nullptr, nullptr);

    // f2 = hid @ W2 + b2
    gemm_bt<EPI_BIAS><<<dim3(4, 128, 1), 256, 0, stream>>>(
        HID, W2t, F2, b2, 2 * D, 2 * D, 2 * D, D, nullptr, nullptr, nullptr, nullptr, nullptr, nullptr);

    // out = LN(f2 + x)  -> fp32 d_out
    ln_kernel_f32out<<<BN * N, 256, 0, stream>>>(F2, X, g2, be2, (float*)d_out);
}

// Round 9
// 521.368 us; speedup vs baseline: 1.0733x; 1.0545x over previous
//
#include <hip/hip_runtime.h>

typedef unsigned short u16;
typedef __bf16 bf16x8 __attribute__((ext_vector_type(8)));
typedef float f32x4 __attribute__((ext_vector_type(4)));

// Problem constants: B=8, N=2048, DH=512
#define SEQN 2048
#define DHID 512

static __device__ __forceinline__ float bf2f(u16 u) {
    union { unsigned int i; float f; } c; c.i = ((unsigned int)u) << 16; return c.f;
}
static __device__ __forceinline__ u16 f2bf(float f) {
    union { float f; unsigned int i; } c; c.f = f;
    unsigned int x = c.i;
    return (u16)((x + 0x7fffu + ((x >> 16) & 1u)) >> 16);
}

// async global->LDS, 16B per lane, LDS dest = wave-uniform base + lane*16
static __device__ __forceinline__ void gld_lds16(const u16* g, u16* l) {
    __builtin_amdgcn_global_load_lds(
        (__attribute__((address_space(1))) void*)(g),
        (__attribute__((address_space(3))) void*)(l), 16, 0, 0);
}

// ---------------------------------------------------------------------------
// Fused prep kernel: replaces cvt(H) + 5x cvt_t(W*) + hmean (7 launches -> 1).
// Block ranges (all branches block-uniform):
//   [0,4096):      H fp32 -> bf16, 8 elems/thread
//   [4096,7168):   Wq|Wk|Wv transpose-cvt into Wqkvt (1024 blocks each)
//   [7168,9216):   W1 [512][1024] -> W1t [1024][512]
//   [9216,11264):  W2 [1024][512] -> W2t [512][1024]
//   [11264,11776): hop_emb row means, 4 rows/block (64 lanes each)
// ---------------------------------------------------------------------------
__global__ __launch_bounds__(256) void prep_kernel(
    const float* __restrict__ H, const float* __restrict__ Wq,
    const float* __restrict__ Wk, const float* __restrict__ Wv,
    const float* __restrict__ W1, const float* __restrict__ W2,
    const float* __restrict__ hop,
    u16* __restrict__ Hb, u16* __restrict__ Wqkvt,
    u16* __restrict__ W1t, u16* __restrict__ W2t, float* __restrict__ hm)
{
    const int bid = blockIdx.x, tid = threadIdx.x;
    if (bid < 4096) {
        int i = (bid * 256 + tid) * 8;             // 8.39M elems
        float4 a = *(const float4*)(H + i);
        float4 c = *(const float4*)(H + i + 4);
        union { uint4 u; u16 s[8]; } o;
        o.s[0] = f2bf(a.x); o.s[1] = f2bf(a.y); o.s[2] = f2bf(a.z); o.s[3] = f2bf(a.w);
        o.s[4] = f2bf(c.x); o.s[5] = f2bf(c.y); o.s[6] = f2bf(c.z); o.s[7] = f2bf(c.w);
        *(uint4*)(Hb + i) = o.u;
    } else if (bid < 7168) {
        int idx = (bid - 4096) * 256 + tid;        // 786432
        int which = idx >> 18;                     // 262144 per matrix
        int rem = idx & 262143;
        int n = rem >> 9, k = rem & 511;
        const float* src = (which == 0) ? Wq : ((which == 1) ? Wk : Wv);
        Wqkvt[idx] = f2bf(src[(size_t)k * 512 + n]);
    } else if (bid < 9216) {
        int idx = (bid - 7168) * 256 + tid;        // 524288; n=idx/512,k=idx%512
        int n = idx >> 9, k = idx & 511;
        W1t[idx] = f2bf(W1[(size_t)k * 1024 + n]);
    } else if (bid < 11264) {
        int idx = (bid - 9216) * 256 + tid;        // 524288; n=idx/1024,k=idx%1024
        int n = idx >> 10, k = idx & 1023;
        W2t[idx] = f2bf(W2[(size_t)k * 512 + n]);
    } else {
        int j = (bid - 11264) * 4 + (tid >> 6);    // 2048 rows, 4/block
        int lane = tid & 63;
        const float* p = hop + (size_t)j * DHID + lane * 8;
        float4 a = *(const float4*)p;
        float4 c = *(const float4*)(p + 4);
        float s = a.x + a.y + a.z + a.w + c.x + c.y + c.z + c.w;
#pragma unroll
        for (int m = 1; m < 64; m <<= 1) s += __shfl_xor(s, m);
        if (lane == 0) hm[j] = s * (1.0f / (float)DHID);
    }
}

// ---------------------------------------------------------------------------
// BT MFMA GEMM v2: C[M,N] = A[M,K] * Bt[N,K]^T + epilogue  (A,Bt,C bf16)
// Tile 128x128x32, 256 threads (4 waves as 2x2 of 64x64), 16x16x32 MFMA.
// DOUBLE-BUFFERED 2-phase. EPI_QKV: N=1536 concat [Q|K|Vt].
// ---------------------------------------------------------------------------
enum { EPI_BIAS = 0, EPI_RELU = 1, EPI_PLAIN = 3, EPI_BIAS_T = 4, EPI_QKV = 5 };

template <int EPI>
__global__ __launch_bounds__(256) void gemm_bt(
    const u16* __restrict__ A, const u16* __restrict__ Bt, u16* __restrict__ C,
    const float* __restrict__ bias,
    int K, int lda, int ldb, int ldc,
    u16* __restrict__ Qo, u16* __restrict__ Ko, u16* __restrict__ Vto,
    const float* __restrict__ bq_, const float* __restrict__ bk_,
    const float* __restrict__ bv_)
{
    __shared__ u16 As[2][128 * 32];   // 16 KB
    __shared__ u16 Bs[2][128 * 32];   // 16 KB

    const int tid = threadIdx.x;
    const u16* Ab = A;
    const u16* Bb = Bt;

    const int bm0 = blockIdx.y * 128, bn0 = blockIdx.x * 128;
    const int wid = tid >> 6, lane = tid & 63, quad = lane >> 4, l16 = lane & 15;
    const int wm = (wid >> 1) * 64, wn = (wid & 1) * 64;
    const int srow = lane >> 2;            // 0..15: row within 16-row chunk
    const int skof = (lane & 3) * 8;       // k element offset (8 bf16 = 16 B)

    f32x4 acc[4][4];
#pragma unroll
    for (int i = 0; i < 4; ++i)
#pragma unroll
        for (int j = 0; j < 4; ++j) acc[i][j] = (f32x4){0.f, 0.f, 0.f, 0.f};

    // prologue: stage K-tile 0 into buf 0
#pragma unroll
    for (int it = 0; it < 2; ++it) {
        int c = wid * 2 + it;              // wave-uniform
        gld_lds16(Ab + (size_t)(bm0 + c * 16 + srow) * lda + skof, &As[0][c * 512]);
    }
#pragma unroll
    for (int it = 0; it < 2; ++it) {
        int c = wid * 2 + it;
        gld_lds16(Bb + (size_t)(bn0 + c * 16 + srow) * ldb + skof, &Bs[0][c * 512]);
    }

    int cur = 0;
    for (int k0 = 0; k0 < K; k0 += 32, cur ^= 1) {
        __syncthreads();   // drains own vmcnt (buf[cur] stage) + lgkm

        if (k0 + 32 < K) {
#pragma unroll
            for (int it = 0; it < 2; ++it) {
                int c = wid * 2 + it;
                gld_lds16(Ab + (size_t)(bm0 + c * 16 + srow) * lda + k0 + 32 + skof,
                          &As[cur ^ 1][c * 512]);
            }
#pragma unroll
            for (int it = 0; it < 2; ++it) {
                int c = wid * 2 + it;
                gld_lds16(Bb + (size_t)(bn0 + c * 16 + srow) * ldb + k0 + 32 + skof,
                          &Bs[cur ^ 1][c * 512]);
            }
        }
        __builtin_amdgcn_sched_barrier(0);   // keep stage issue above compute

        bf16x8 af[4], bfr[4];
#pragma unroll
        for (int i = 0; i < 4; ++i)
            af[i] = *(const bf16x8*)&As[cur][(wm + i * 16 + l16) * 32 + quad * 8];
#pragma unroll
        for (int j = 0; j < 4; ++j)
            bfr[j] = *(const bf16x8*)&Bs[cur][(wn + j * 16 + l16) * 32 + quad * 8];
#pragma unroll
        for (int i = 0; i < 4; ++i)
#pragma unroll
            for (int j = 0; j < 4; ++j)
                acc[i][j] = __builtin_amdgcn_mfma_f32_16x16x32_bf16(af[i], bfr[j], acc[i][j], 0, 0, 0);
    }

    // ---- epilogue: C/D layout col=lane&15, row=quad*4+reg ----
#pragma unroll
    for (int i = 0; i < 4; ++i) {
#pragma unroll
        for (int j = 0; j < 4; ++j) {
            const int gn = bn0 + wn + j * 16 + l16;
            const int gm0 = bm0 + wm + i * 16 + quad * 4;
            if constexpr (EPI == EPI_BIAS || EPI == EPI_RELU) {
                const float b = bias[gn];
#pragma unroll
                for (int r = 0; r < 4; ++r) {
                    float v = acc[i][j][r] + b;
                    if constexpr (EPI == EPI_RELU) v = fmaxf(v, 0.f);
                    C[(size_t)(gm0 + r) * ldc + gn] = f2bf(v);
                }
            } else if constexpr (EPI == EPI_QKV) {
                const int sel = gn >> 9;     // block-uniform (bn0 128-aligned)
                const int n = gn & 511;
                if (sel == 0) {
                    const float b = bq_[n];
#pragma unroll
                    for (int r = 0; r < 4; ++r)
                        Qo[(size_t)(gm0 + r) * DHID + n] = f2bf(acc[i][j][r] + b);
                } else if (sel == 1) {
                    const float b = bk_[n];
#pragma unroll
                    for (int r = 0; r < 4; ++r)
                        Ko[(size_t)(gm0 + r) * DHID + n] = f2bf(acc[i][j][r] + b);
                } else {
                    const float b = bv_[n];
                    const int bb = gm0 >> 11, nn2 = gm0 & 2047;
                    ushort4 o;
                    o.x = f2bf(acc[i][j][0] + b);
                    o.y = f2bf(acc[i][j][1] + b);
                    o.z = f2bf(acc[i][j][2] + b);
                    o.w = f2bf(acc[i][j][3] + b);
                    *(ushort4*)&Vto[((size_t)bb * 512 + n) * 2048 + nn2] = o;
                }
            } else {
#pragma unroll
                for (int r = 0; r < 4; ++r)
                    C[(size_t)(gm0 + r) * ldc + gn] = f2bf(acc[i][j][r]);
            }
        }
    }
}

// ---------------------------------------------------------------------------
// Fused attention v11 = v8 loop (best measured: 192us) + LN1 fused epilogue.
// Block = (batch bx, 32 Q-rows by). 4 waves: wave w -> rows (w>>1)*16;
// kv-half (QK^T) and d-half (PV) = w&1. Loop identical to v8.
// Fused LN1 epilogue: x = attn_out + H (fp32 H read direct); per-row
// mean/var via l16-group shfl + cross-pair LDS exchange; writes
// X = LN(x)*g1+be1 directly (kills LN1 kernel + AO round-trip). X must NOT
// alias K/V (other blocks still read K/V while this one finalizes) -> X
// lives in the old AO region.
// LDS 68096B: Ks 32KB | Vs 32KB | Pb 2.5KB -> 2 blocks/CU.
// ---------------------------------------------------------------------------
__global__ __launch_bounds__(256, 2) void attn_kernel(
    const u16* __restrict__ Q, const u16* __restrict__ K, const u16* __restrict__ Vt,
    const float* __restrict__ adj, const float* __restrict__ hm,
    const float* __restrict__ Hf, const float* __restrict__ g1,
    const float* __restrict__ be1, u16* __restrict__ X)
{
    extern __shared__ u16 lds[];                 // 68096 B
    u16* Ks = lds;                               // [ds16][c2][16 rows x 32 u16]
    u16* Vs = lds + 16384;                       // [d512][kv32]
    u16* Pb = lds + 32768;                       // 2 row-groups x 640 u16

    const int tid = threadIdx.x, wid = tid >> 6, lane = tid & 63;
    const int quad = lane >> 4, l16 = lane & 15;
    const int b = blockIdx.x;                    // batch -> XCD affinity
    const int q0 = blockIdx.y * 32 + (wid >> 1) * 16;  // wave's 16 Q-rows
    const int ch = wid & 1;                      // kv-half (QK^T) / d-half (PV)
    const int D0 = ch * 256;
    const int srow = lane >> 2, sko = (lane & 3) * 8;

    const u16* Qg = Q + (size_t)b * SEQN * DHID;
    const u16* Kg = K + (size_t)b * SEQN * DHID;
    const u16* Vg = Vt + (size_t)b * DHID * SEQN;
    const float* adjg = adj + (size_t)b * SEQN * SEQN;
    u16* Xg = X + (size_t)b * SEQN * DHID;
    const float* arow = adjg + (size_t)(q0 + quad * 4) * SEQN;
    u16* Pg = Pb + (wid >> 1) * 640;             // shared by the d-half pair

    const float scale = 0.044194173824159216f;   // 1/sqrt(512)

    // Q fragments (A-layout): lane holds Q[q0+l16][ds*32+quad*8+j]
    bf16x8 qf[16];
#pragma unroll
    for (int ds = 0; ds < 16; ++ds)
        qf[ds] = *(const bf16x8*)(Qg + (size_t)(q0 + l16) * DHID + ds * 32 + quad * 8);

    f32x4 oacc[16];
#pragma unroll
    for (int dt = 0; dt < 16; ++dt) oacc[dt] = (f32x4){0.f, 0.f, 0.f, 0.f};
    float lsum[4] = {0.f, 0.f, 0.f, 0.f};

    // ---- prologue: issue Ks = K[0] staging; drained by first B1 ----
#pragma unroll
    for (int i = 0; i < 8; ++i) {
        int id = wid * 8 + i, ds = id >> 1, c = id & 1;
        gld_lds16(Kg + (size_t)(c * 16 + srow) * DHID + ds * 32 + sko,
                  &Ks[ds * 1024 + c * 512]);
    }

    for (int kt = 0; kt < 64; ++kt) {
        const int kv0 = kt * 32;

        // [B1] drains own vmcnt (K[kt] stage) + lgkm (prev PV/pf reads), barrier.
        __syncthreads();

        // ---- stage Vs[kt] async (drained at B2, covered by QK^T) ----
#pragma unroll
        for (int i = 0; i < 8; ++i) {
            int id = wid * 8 + i;                // d-rows id*16..id*16+16
            gld_lds16(Vg + (size_t)(id * 16 + srow) * SEQN + kv0 + sko,
                      &Vs[id * 512]);
        }

        // ---- scalar loads for the wave's 16 kv-cols (used post-B2) ----
        float hv = hm[kv0 + ch * 16 + l16] * scale;
        float av[4];
#pragma unroll
        for (int r = 0; r < 4; ++r)
            av[r] = arow[(size_t)r * SEQN + kv0 + ch * 16 + l16];

        // ---- QK^T: S 16x16 (wave's kv-half), 2 chains, reads Ks[.][ch] ----
        f32x4 sa = {0.f,0.f,0.f,0.f}, sb = {0.f,0.f,0.f,0.f};
#pragma unroll
        for (int ds = 0; ds < 16; ds += 2) {
            bf16x8 k0 = *(const bf16x8*)&Ks[ds * 1024 + ch * 512 + l16 * 32 + quad * 8];
            sa = __builtin_amdgcn_mfma_f32_16x16x32_bf16(qf[ds], k0, sa, 0, 0, 0);
            bf16x8 k1 = *(const bf16x8*)&Ks[(ds + 1) * 1024 + ch * 512 + l16 * 32 + quad * 8];
            sb = __builtin_amdgcn_mfma_f32_16x16x32_bf16(qf[ds + 1], k1, sb, 0, 0, 0);
        }
        f32x4 s = sa + sb;

        // [B2] drains own vmcnt (Vs + scalars) + lgkm (Ks reads), barrier.
        __syncthreads();

        // ---- stage Ks[kt+1] NOW (drained at next B1; softmax+PV cover) ----
        if (kt < 63) {
#pragma unroll
            for (int i = 0; i < 8; ++i) {
                int id = wid * 8 + i, ds = id >> 1, c = id & 1;
                gld_lds16(Kg + (size_t)(kv0 + 32 + c * 16 + srow) * DHID + ds * 32 + sko,
                          &Ks[ds * 1024 + c * 512]);
            }
        }
        __builtin_amdgcn_sched_barrier(0);       // keep K issue above softmax/PV

        // ---- softmax: 4 exp, write wave's P columns into shared Pg ----
#pragma unroll
        for (int r = 0; r < 4; ++r) {
            float p = __expf(s[r] * av[r] * hv);
            lsum[r] += p;                         // wave's kv-half partial sum
            Pg[(quad * 4 + r) * 40 + ch * 16 + l16] = f2bf(p);
        }

        // [B3] P complete across the pair: own lgkm drain + raw barrier.
        asm volatile("s_waitcnt lgkmcnt(0)" ::: "memory");
        __builtin_amdgcn_s_barrier();
        __builtin_amdgcn_sched_barrier(0);

        bf16x8 pf = *(const bf16x8*)&Pg[l16 * 40 + quad * 8];

        // ---- PV: O[16 x 256] += P[16x32] @ V[32 x d-half] ----
#pragma unroll
        for (int dt = 0; dt < 16; ++dt) {
            bf16x8 vf = *(const bf16x8*)&Vs[(D0 + dt * 16 + l16) * 32 + quad * 8];
            oacc[dt] = __builtin_amdgcn_mfma_f32_16x16x32_bf16(pf, vf, oacc[dt], 0, 0, 0);
        }
    }

    // ---- finalize 1: combine kv-half row sums across the pair ----
#pragma unroll
    for (int r = 0; r < 4; ++r) {
#pragma unroll
        for (int m = 1; m < 16; m <<= 1) lsum[r] += __shfl_xor(lsum[r], m);
    }
    __syncthreads();                             // last PV/pf reads done
    float* SUMS = (float*)Pb;
    if (l16 == 0) {
#pragma unroll
        for (int r = 0; r < 4; ++r) SUMS[wid * 16 + quad * 4 + r] = lsum[r];
    }
    __syncthreads();
#pragma unroll
    for (int r = 0; r < 4; ++r)
        lsum[r] = 1.f / (lsum[r] + SUMS[(wid ^ 1) * 16 + quad * 4 + r]);

    // ---- finalize 2 (fused LN1): x = ao + H; row stats ----
    const float* Hfg = Hf + (size_t)b * SEQN * DHID;
    float sr[4] = {0.f, 0.f, 0.f, 0.f}, sq[4] = {0.f, 0.f, 0.f, 0.f};
#pragma unroll
    for (int dt = 0; dt < 16; ++dt) {
#pragma unroll
        for (int r = 0; r < 4; ++r) {
            float h = Hfg[(size_t)(q0 + quad * 4 + r) * DHID + D0 + dt * 16 + l16];
            float x = oacc[dt][r] * lsum[r] + h;
            oacc[dt][r] = x;
            sr[r] += x; sq[r] += x * x;
        }
    }
#pragma unroll
    for (int r = 0; r < 4; ++r) {
#pragma unroll
        for (int m = 1; m < 16; m <<= 1) {
            sr[r] += __shfl_xor(sr[r], m);
            sq[r] += __shfl_xor(sq[r], m);
        }
    }
    __syncthreads();                             // lsum SUMS reads done
    if (l16 == 0) {
#pragma unroll
        for (int r = 0; r < 4; ++r) {
            SUMS[(wid * 16 + quad * 4 + r) * 2]     = sr[r];
            SUMS[(wid * 16 + quad * 4 + r) * 2 + 1] = sq[r];
        }
    }
    __syncthreads();
    float mean[4], rstd[4];
#pragma unroll
    for (int r = 0; r < 4; ++r) {
        float S  = sr[r] + SUMS[((wid ^ 1) * 16 + quad * 4 + r) * 2];
        float Q2 = sq[r] + SUMS[((wid ^ 1) * 16 + quad * 4 + r) * 2 + 1];
        mean[r] = S * (1.f / (float)DHID);
        float var = Q2 * (1.f / (float)DHID) - mean[r] * mean[r];
        rstd[r] = rsqrtf(var + 1e-5f);
    }
#pragma unroll
    for (int dt = 0; dt < 16; ++dt) {
        float gv  = g1[D0 + dt * 16 + l16];
        float bev = be1[D0 + dt * 16 + l16];
#pragma unroll
        for (int r = 0; r < 4; ++r) {
            Xg[(size_t)(q0 + quad * 4 + r) * DHID + D0 + dt * 16 + l16] =
                f2bf((oacc[dt][r] - mean[r]) * rstd[r] * gv + bev);
        }
    }
}

// ---------------------------------------------------------------------------
// LN2: out = LN(a + b) * g + be   (a,b bf16, out fp32)
// ---------------------------------------------------------------------------
__global__ __launch_bounds__(256) void ln_kernel_f32out(
    const u16* __restrict__ a, const u16* __restrict__ bp,
    const float* __restrict__ g, const float* __restrict__ be,
    float* __restrict__ out)
{
    size_t row = blockIdx.x;
    int t = threadIdx.x, wid = t >> 6, lane = t & 63;
    unsigned int va = *(const unsigned int*)(a + row * (size_t)DHID + t * 2);
    unsigned int vb = *(const unsigned int*)(bp + row * (size_t)DHID + t * 2);
    float x0 = bf2f((u16)(va & 0xffff)) + bf2f((u16)(vb & 0xffff));
    float x1 = bf2f((u16)(va >> 16)) + bf2f((u16)(vb >> 16));
    float s = x0 + x1, sq = x0 * x0 + x1 * x1;
#pragma unroll
    for (int m = 1; m < 64; m <<= 1) { s += __shfl_xor(s, m); sq += __shfl_xor(sq, m); }
    __shared__ float rs[4], rq[4];
    if (lane == 0) { rs[wid] = s; rq[wid] = sq; }
    __syncthreads();
    s = rs[0] + rs[1] + rs[2] + rs[3];
    sq = rq[0] + rq[1] + rq[2] + rq[3];
    float mean = s * (1.f / (float)DHID);
    float var = sq * (1.f / (float)DHID) - mean * mean;
    float rstd = rsqrtf(var + 1e-5f);
    float2 vg = *(const float2*)(g + t * 2);
    float2 vbe = *(const float2*)(be + t * 2);
    float y0 = (x0 - mean) * rstd * vg.x + vbe.x;
    float y1 = (x1 - mean) * rstd * vg.y + vbe.y;
    *(float2*)(out + row * (size_t)DHID + t * 2) = make_float2(y0, y1);
}

// ---------------------------------------------------------------------------
extern "C" void kernel_launch(void* const* d_in, const int* in_sizes, int n_in,
                              void* d_out, int out_size, void* d_ws, size_t ws_size,
                              hipStream_t stream) {
    const float* H   = (const float*)d_in[0];
    const float* adj = (const float*)d_in[1];
    const float* hop = (const float*)d_in[2];
    const float* Wq  = (const float*)d_in[3];
    const float* bq  = (const float*)d_in[4];
    const float* Wk  = (const float*)d_in[5];
    const float* bk  = (const float*)d_in[6];
    const float* Wv  = (const float*)d_in[7];
    const float* bv  = (const float*)d_in[8];
    const float* W1  = (const float*)d_in[9];
    const float* b1  = (const float*)d_in[10];
    const float* W2  = (const float*)d_in[11];
    const float* b2  = (const float*)d_in[12];
    const float* g1  = (const float*)d_in[13];
    const float* be1 = (const float*)d_in[14];
    const float* g2  = (const float*)d_in[15];
    const float* be2 = (const float*)d_in[16];

    const size_t MiB = 1ull << 20;
    char* w = (char*)d_ws;
    float* hm   = (float*)w;                      // 8 KB
    u16* Hb    = (u16*)(w + 1 * MiB);             // 16 MiB
    u16* Wqkvt = (u16*)(w + 17 * MiB);            // 1.5 MiB [Wq^T|Wk^T|Wv^T]
    u16* W1t   = (u16*)(w + 18 * MiB + 512 * 1024); // 1 MiB
    u16* W2t   = (u16*)(w + 19 * MiB + 512 * 1024); // 1 MiB
    u16* Q     = (u16*)(w + 21 * MiB);            // 16 MiB
    u16* Kb    = (u16*)(w + 37 * MiB);            // 16 MiB
    u16* Vt    = (u16*)(w + 53 * MiB);            // 16 MiB  [b][512][2048]
    u16* X     = (u16*)(w + 69 * MiB);            // 16 MiB (LN1 out; old AO slot)
    u16* HID   = (u16*)(w + 85 * MiB);            // 32 MiB -> total 117 MiB
    // alias (lifetimes disjoint):
    u16* F2  = Vt;   // ffn2 output (V dead after attention)

    const int BN = 8, N = SEQN, D = DHID;

    // fused prep: H cvt + 5 weight transpose-cvts + hop means (1 launch)
    prep_kernel<<<11776, 256, 0, stream>>>(H, Wq, Wk, Wv, W1, W2, hop,
                                           Hb, Wqkvt, W1t, W2t, hm);

    // fused QKV: C[16384,1536] over [Q|K|Vt] outputs
    gemm_bt<EPI_QKV><<<dim3(12, 128, 1), 256, 0, stream>>>(
        Hb, Wqkvt, nullptr, nullptr, D, D, D, 0, Q, Kb, Vt, bq, bk, bv);

    // fused attention + LN1: 512 blocks, writes X = LN(attn+H)*g1+be1
    attn_kernel<<<dim3(8, 64), 256, 68096, stream>>>(Q, Kb, Vt, adj, hm,
                                                     H, g1, be1, X);

    // hid = relu(x @ W1 + b1)
    gemm_bt<EPI_RELU><<<dim3(8, 128, 1), 256, 0, stream>>>(
        X, W1t, HID, b1, D, D, D, 2 * D, nullptr, nullptr, nullptr, nullptr, nullptr, nullptr);

    // f2 = hid @ W2 + b2
    gemm_bt<EPI_BIAS><<<dim3(4, 128, 1), 256, 0, stream>>>(
        HID, W2t, F2, b2, 2 * D, 2 * D, 2 * D, D, nullptr, nullptr, nullptr, nullptr, nullptr, nullptr);

    // out = LN(f2 + x)  -> fp32 d_out
    ln_kernel_f32out<<<BN * N, 256, 0, stream>>>(F2, X, g2, be2, (float*)d_out);
}